// Round 1
// 814.926 us; speedup vs baseline: 3.2356x; 3.2356x over previous
//
#include <hip/hip_runtime.h>
#include <hip/hip_bf16.h>
#include <math.h>

#define BB 32
#define NN 24564
#define CC 81
#define CM1 80
#define KK 100
#define CAP 512
#define CONF 0.01f
#define NMSTHR 0.45f

#define TROWS 64                      // rows per softmax tile
#define TPB ((NN + TROWS - 1) / TROWS)  // 384 tiles per batch image

// correctly-rounded fp32 exp via double (closest match to np.exp float32)
__device__ __forceinline__ float fexp_cr(float x) {
    return (float)exp((double)x);
}

// ---------------------------------------------------------------------------
// Kernel A: tiled softmax over C=81. One block stages 64 contiguous rows of
// one batch image into LDS (coalesced float4 loads), wave 0 computes per-row
// max / pairwise-sum EXACTLY as the previous per-thread version (bit-identical:
// same sequential max order, same 8-accumulator pairwise sum, expf computed
// once and reused), then all 256 threads emit:
//   - scores [B,N,C]   : coalesced float4 stores (linear tile layout)
//   - fg [B,C-1,N]     : transposed, 64-contiguous-n segments, float4 stores
// LDS stride-81 reads are bank-conflict-free (gcd(81,32)=1 -> <=2 lanes/bank).
// ---------------------------------------------------------------------------
__global__ __launch_bounds__(256) void softmax_kernel(const float* __restrict__ logits,
                                                      float* __restrict__ scores,
                                                      float* __restrict__ fg, int use_fg) {
#pragma clang fp contract(off)
    __shared__ __align__(16) float tile[TROWS * CC];   // 20736 B
    __shared__ float sres[TROWS];

    const int blk = blockIdx.x;
    const int b = blk / TPB;
    const int t = blk - b * TPB;
    const int n0 = t * TROWS;
    int rows = NN - n0;
    if (rows > TROWS) rows = TROWS;
    const int tid = threadIdx.x;

    // ---- phase 1: coalesced float4 load of the tile into LDS ----
    // rows*CC is always divisible by 4 (64*81=5184, 52*81=4212)
    const float4* src4 = (const float4*)(logits + ((size_t)b * NN + n0) * CC);
    float4* tile4 = (float4*)tile;
    const int total4 = (rows * CC) >> 2;
    for (int i = tid; i < total4; i += 256) tile4[i] = src4[i];
    __syncthreads();

    // ---- phase 2: per-row max + pairwise sum (bit-identical to previous) ----
    if (tid < rows) {
        float* x = tile + tid * CC;
        float m = x[0];
        for (int c = 1; c < CC; ++c) m = fmaxf(m, x[c]);

        float r[8];
#pragma unroll
        for (int j = 0; j < 8; ++j) {
            float e = expf(x[j] - m);
            x[j] = e;                   // store exp in place (same bits reused)
            r[j] = e;
        }
        for (int i = 8; i < 80; i += 8) {
#pragma unroll
            for (int j = 0; j < 8; ++j) {
                float e = expf(x[i + j] - m);
                x[i + j] = e;
                r[j] += e;
            }
        }
        float res = ((r[0] + r[1]) + (r[2] + r[3])) + ((r[4] + r[5]) + (r[6] + r[7]));
        float e80 = expf(x[80] - m);
        x[80] = e80;
        res += e80;
        sres[tid] = res;
    }
    __syncthreads();

    // ---- phase 3: scores = e/res, coalesced float4 store + LDS overwrite ----
    float4* dst4 = (float4*)(scores + ((size_t)b * NN + n0) * CC);
    for (int i = tid; i < total4; i += 256) {
        float4 v = tile4[i];
        int e0 = i << 2;
        unsigned r0 = (unsigned)(e0    ) / 81u;
        unsigned r1 = (unsigned)(e0 + 1) / 81u;
        unsigned r2 = (unsigned)(e0 + 2) / 81u;
        unsigned r3 = (unsigned)(e0 + 3) / 81u;
        v.x = v.x / sres[r0];
        v.y = v.y / sres[r1];
        v.z = v.z / sres[r2];
        v.w = v.w / sres[r3];
        dst4[i] = v;                   // coalesced global store
        tile4[i] = v;                  // keep sc in LDS for transposed fg pass
    }
    __syncthreads();

    // ---- phase 4: fg[b, c, n] transposed writes, float4 over n ----
    if (use_fg) {
        const int rows4 = rows >> 2;   // 16 or 13, rows always divisible by 4
        // idx -> (c = idx>>4 in [0,80), j4 = idx&15); lanes with same c write
        // 4*16=64 contiguous n -> fully coalesced 256B+ segments
        for (int idx = tid; idx < CM1 * (TROWS >> 2); idx += 256) {
            int c  = idx >> 4;
            int j4 = idx & 15;
            if (j4 < rows4) {
                int j = j4 << 2;
                float4 v;
                v.x = tile[(j    ) * CC + (c + 1)];
                v.y = tile[(j + 1) * CC + (c + 1)];
                v.z = tile[(j + 2) * CC + (c + 1)];
                v.w = tile[(j + 3) * CC + (c + 1)];
                *(float4*)(fg + ((size_t)(b * CM1 + c)) * NN + n0 + j) = v;
            }
        }
    }
}

// ---------------------------------------------------------------------------
// Kernel B: decode boxes for all (b, n). Mirrors reference op order exactly.
// ---------------------------------------------------------------------------
__global__ __launch_bounds__(256) void decode_kernel(const float* __restrict__ loc,
                                                     const float* __restrict__ priors,
                                                     float* __restrict__ boxes) {
#pragma clang fp contract(off)
    int row = blockIdx.x * 256 + threadIdx.x;
    if (row >= BB * NN) return;
    int n = row % NN;
    float4 L = ((const float4*)loc)[row];
    float4 P = ((const float4*)priors)[n];
    float cx = (L.x * 0.1f) * P.z + P.x;
    float cy = (L.y * 0.1f) * P.w + P.y;
    float w  = fexp_cr(L.z * 0.2f) * P.z;
    float h  = fexp_cr(L.w * 0.2f) * P.w;
    float4 o;
    o.x = cx - w * 0.5f;   // wh/2 == wh*0.5f exactly
    o.y = cy - h * 0.5f;
    o.z = cx + w * 0.5f;
    o.w = cy + h * 0.5f;
    ((float4*)boxes)[row] = o;
}

// ---------------------------------------------------------------------------
// Kernel C: per (b, c) block — exact top-100 via radix-select on float bits,
// stable-sorted (value desc, index asc), then greedy NMS, then outputs.
// ---------------------------------------------------------------------------
__global__ __launch_bounds__(256) void topk_nms_kernel(
    const float* __restrict__ scores, const float* __restrict__ fg, int use_fg,
    const float* __restrict__ boxes,
    float* __restrict__ nms_scores, float* __restrict__ nms_boxes,
    float* __restrict__ keep_out)
{
#pragma clang fp contract(off)
    const int blk = blockIdx.x;        // b*80 + c
    const int b = blk / CM1;
    const int c = blk - b * CM1;
    const int tid = threadIdx.x;

    __shared__ unsigned hist[4096];
    __shared__ unsigned partial[256];
    __shared__ unsigned long long cand[CAP];
    __shared__ unsigned scnt;
    __shared__ unsigned s_T;
    __shared__ int s_b1, s_above, s_refine;
    __shared__ float sbx[KK][4];
    __shared__ float sarea[KK];
    __shared__ float sscore[KK];
    __shared__ int skeep[KK];

    const float* src;
    size_t stride;
    if (use_fg) { src = fg + ((size_t)(b * CM1 + c)) * NN; stride = 1; }
    else        { src = scores + ((size_t)b * NN) * CC + (c + 1); stride = CC; }

    // ---- pass 1: histogram on top 12 bits (values are positive floats) ----
    for (int i = tid; i < 4096; i += 256) hist[i] = 0u;
    __syncthreads();
    for (int n = tid; n < NN; n += 256) {
        unsigned bits = __float_as_uint(src[(size_t)n * stride]);
        atomicAdd(&hist[bits >> 20], 1u);
    }
    __syncthreads();
    unsigned psum = 0;
    for (int j = 0; j < 16; ++j) psum += hist[tid * 16 + j];
    partial[tid] = psum;
    __syncthreads();
    if (tid == 0) {
        unsigned acc = 0; int b1 = 0;
        for (int t = 255; t >= 0; --t) {
            if (acc + partial[t] >= (unsigned)KK) {
                for (int bin = t * 16 + 15; ; --bin) {
                    if (acc + hist[bin] >= (unsigned)KK) { b1 = bin; break; }
                    acc += hist[bin];
                }
                break;
            }
            acc += partial[t];
        }
        s_b1 = b1;
        s_above = (int)acc;                       // strictly above bin b1
        s_refine = (acc + hist[b1] > CAP) ? 1 : 0;
        s_T = ((unsigned)b1) << 20;
    }
    __syncthreads();

    // ---- optional refine on bits [19:8] if bin too dense ----
    if (s_refine) {
        int b1 = s_b1;
        for (int i = tid; i < 4096; i += 256) hist[i] = 0u;
        __syncthreads();
        for (int n = tid; n < NN; n += 256) {
            unsigned bits = __float_as_uint(src[(size_t)n * stride]);
            if ((int)(bits >> 20) == b1) atomicAdd(&hist[(bits >> 8) & 0xFFFu], 1u);
        }
        __syncthreads();
        psum = 0;
        for (int j = 0; j < 16; ++j) psum += hist[tid * 16 + j];
        partial[tid] = psum;
        __syncthreads();
        if (tid == 0) {
            int K2 = KK - s_above;
            unsigned acc = 0; int b2 = 0;
            for (int t = 255; t >= 0; --t) {
                if ((int)(acc + partial[t]) >= K2) {
                    for (int bin = t * 16 + 15; ; --bin) {
                        if ((int)(acc + hist[bin]) >= K2) { b2 = bin; break; }
                        acc += hist[bin];
                    }
                    break;
                }
                acc += partial[t];
            }
            s_T = (((unsigned)s_b1) << 20) | (((unsigned)b2) << 8);
        }
        __syncthreads();
    }

    // ---- collect candidates >= T ----
    if (tid == 0) scnt = 0u;
    __syncthreads();
    unsigned T = s_T;
    for (int n = tid; n < NN; n += 256) {
        unsigned bits = __float_as_uint(src[(size_t)n * stride]);
        if (bits >= T) {
            unsigned pos = atomicAdd(&scnt, 1u);
            if (pos < CAP) {
                cand[pos] = (((unsigned long long)bits) << 32)
                          | (unsigned)(0xFFFFFFFFu - (unsigned)n);
            }
        }
    }
    __syncthreads();
    unsigned cnt = scnt; if (cnt > CAP) cnt = CAP;
    for (int i = tid; i < CAP; i += 256) {
        if ((unsigned)i >= cnt) cand[i] = 0ull;
    }
    __syncthreads();

    // ---- bitonic sort, descending, CAP=512 elements, 256 threads ----
    for (unsigned k = 2; k <= CAP; k <<= 1) {
        for (unsigned j = k >> 1; j > 0; j >>= 1) {
            for (unsigned e = tid; e < CAP; e += 256) {
                unsigned ixj = e ^ j;
                if (ixj > e) {
                    unsigned long long a = cand[e], bb2 = cand[ixj];
                    bool desc = ((e & k) == 0);
                    if (desc ? (a < bb2) : (a > bb2)) { cand[e] = bb2; cand[ixj] = a; }
                }
            }
            __syncthreads();
        }
    }

    // ---- extract top-100, gather decoded boxes ----
    if (tid < KK) {
        unsigned long long key = cand[tid];
        unsigned bits = (unsigned)(key >> 32);
        unsigned n = 0xFFFFFFFFu - (unsigned)(key & 0xFFFFFFFFu);
        float s = __uint_as_float(bits);
        sscore[tid] = s;
        skeep[tid] = (s > CONF) ? 1 : 0;
        float4 bx = ((const float4*)boxes)[(size_t)b * NN + n];
        sbx[tid][0] = bx.x; sbx[tid][1] = bx.y; sbx[tid][2] = bx.z; sbx[tid][3] = bx.w;
        sarea[tid] = fmaxf(bx.z - bx.x, 0.f) * fmaxf(bx.w - bx.y, 0.f);
    }
    __syncthreads();

    // ---- greedy NMS (reference semantics: only kept boxes suppress) ----
    for (int i = 0; i < KK - 1; ++i) {
        if (skeep[i]) {
            int j = i + 1 + tid;
            if (j < KK) {
                float xx1 = fmaxf(sbx[i][0], sbx[j][0]);
                float yy1 = fmaxf(sbx[i][1], sbx[j][1]);
                float xx2 = fminf(sbx[i][2], sbx[j][2]);
                float yy2 = fminf(sbx[i][3], sbx[j][3]);
                float w = fmaxf(xx2 - xx1, 0.f);
                float h = fmaxf(yy2 - yy1, 0.f);
                float inter = w * h;
                float den = ((sarea[i] + sarea[j]) - inter) + 1e-8f;
                if (inter / den > NMSTHR) skeep[j] = 0;
            }
        }
        __syncthreads();
    }

    // ---- outputs ----
    if (tid < KK) {
        int kf = skeep[tid];
        size_t oidx = (size_t)blk * KK + tid;
        nms_scores[oidx] = kf ? sscore[tid] : 0.f;
        keep_out[oidx]   = kf ? 1.f : 0.f;
        float4 ob;
        ob.x = kf ? sbx[tid][0] : 0.f;
        ob.y = kf ? sbx[tid][1] : 0.f;
        ob.z = kf ? sbx[tid][2] : 0.f;
        ob.w = kf ? sbx[tid][3] : 0.f;
        ((float4*)nms_boxes)[oidx] = ob;
    }
}

extern "C" void kernel_launch(void* const* d_in, const int* in_sizes, int n_in,
                              void* d_out, int out_size, void* d_ws, size_t ws_size,
                              hipStream_t stream) {
    const float* logits = (const float*)d_in[0];
    const float* bbox   = (const float*)d_in[1];
    const float* priors = (const float*)d_in[2];

    float* out = (float*)d_out;
    float* scores     = out;
    float* boxes      = scores + (size_t)BB * NN * CC;
    float* nms_scores = boxes + (size_t)BB * NN * 4;
    float* nms_boxes  = nms_scores + (size_t)BB * CM1 * KK;
    float* keep_out   = nms_boxes + (size_t)BB * CM1 * KK * 4;

    size_t fg_bytes = (size_t)BB * CM1 * NN * sizeof(float);
    int use_fg = (ws_size >= fg_bytes) ? 1 : 0;
    float* fg = (float*)d_ws;

    int rows = BB * NN;
    int blocksA = (rows + 255) / 256;
    softmax_kernel<<<BB * TPB, 256, 0, stream>>>(logits, scores, fg, use_fg);
    decode_kernel<<<blocksA, 256, 0, stream>>>(bbox, priors, boxes);
    topk_nms_kernel<<<BB * CM1, 256, 0, stream>>>(scores, fg, use_fg, boxes,
                                                  nms_scores, nms_boxes, keep_out);
}

// Round 2
// 692.174 us; speedup vs baseline: 3.8094x; 1.1773x over previous
//
#include <hip/hip_runtime.h>
#include <hip/hip_bf16.h>
#include <math.h>

#define BB 32
#define NN 24564
#define CC 81
#define CM1 80
#define KK 100
#define CAP 256
#define CONF 0.01f
#define NMSTHR 0.45f

#define TROWS 64                      // rows per softmax tile
#define TPB ((NN + TROWS - 1) / TROWS)  // 384 tiles per batch image

// correctly-rounded fp32 exp via double (closest match to np.exp float32)
__device__ __forceinline__ float fexp_cr(float x) {
    return (float)exp((double)x);
}

// ---------------------------------------------------------------------------
// Kernel A: tiled softmax over C=81 (unchanged from R1 — verified).
// ---------------------------------------------------------------------------
__global__ __launch_bounds__(256) void softmax_kernel(const float* __restrict__ logits,
                                                      float* __restrict__ scores,
                                                      float* __restrict__ fg, int use_fg) {
#pragma clang fp contract(off)
    __shared__ __align__(16) float tile[TROWS * CC];   // 20736 B
    __shared__ float sres[TROWS];

    const int blk = blockIdx.x;
    const int b = blk / TPB;
    const int t = blk - b * TPB;
    const int n0 = t * TROWS;
    int rows = NN - n0;
    if (rows > TROWS) rows = TROWS;
    const int tid = threadIdx.x;

    const float4* src4 = (const float4*)(logits + ((size_t)b * NN + n0) * CC);
    float4* tile4 = (float4*)tile;
    const int total4 = (rows * CC) >> 2;
    for (int i = tid; i < total4; i += 256) tile4[i] = src4[i];
    __syncthreads();

    if (tid < rows) {
        float* x = tile + tid * CC;
        float m = x[0];
        for (int c = 1; c < CC; ++c) m = fmaxf(m, x[c]);

        float r[8];
#pragma unroll
        for (int j = 0; j < 8; ++j) {
            float e = expf(x[j] - m);
            x[j] = e;
            r[j] = e;
        }
        for (int i = 8; i < 80; i += 8) {
#pragma unroll
            for (int j = 0; j < 8; ++j) {
                float e = expf(x[i + j] - m);
                x[i + j] = e;
                r[j] += e;
            }
        }
        float res = ((r[0] + r[1]) + (r[2] + r[3])) + ((r[4] + r[5]) + (r[6] + r[7]));
        float e80 = expf(x[80] - m);
        x[80] = e80;
        res += e80;
        sres[tid] = res;
    }
    __syncthreads();

    float4* dst4 = (float4*)(scores + ((size_t)b * NN + n0) * CC);
    for (int i = tid; i < total4; i += 256) {
        float4 v = tile4[i];
        int e0 = i << 2;
        unsigned r0 = (unsigned)(e0    ) / 81u;
        unsigned r1 = (unsigned)(e0 + 1) / 81u;
        unsigned r2 = (unsigned)(e0 + 2) / 81u;
        unsigned r3 = (unsigned)(e0 + 3) / 81u;
        v.x = v.x / sres[r0];
        v.y = v.y / sres[r1];
        v.z = v.z / sres[r2];
        v.w = v.w / sres[r3];
        dst4[i] = v;
        tile4[i] = v;
    }
    __syncthreads();

    if (use_fg) {
        const int rows4 = rows >> 2;
        for (int idx = tid; idx < CM1 * (TROWS >> 2); idx += 256) {
            int c  = idx >> 4;
            int j4 = idx & 15;
            if (j4 < rows4) {
                int j = j4 << 2;
                float4 v;
                v.x = tile[(j    ) * CC + (c + 1)];
                v.y = tile[(j + 1) * CC + (c + 1)];
                v.z = tile[(j + 2) * CC + (c + 1)];
                v.w = tile[(j + 3) * CC + (c + 1)];
                *(float4*)(fg + ((size_t)(b * CM1 + c)) * NN + n0 + j) = v;
            }
        }
    }
}

// ---------------------------------------------------------------------------
// Kernel B: decode boxes (unchanged).
// ---------------------------------------------------------------------------
__global__ __launch_bounds__(256) void decode_kernel(const float* __restrict__ loc,
                                                     const float* __restrict__ priors,
                                                     float* __restrict__ boxes) {
#pragma clang fp contract(off)
    int row = blockIdx.x * 256 + threadIdx.x;
    if (row >= BB * NN) return;
    int n = row % NN;
    float4 L = ((const float4*)loc)[row];
    float4 P = ((const float4*)priors)[n];
    float cx = (L.x * 0.1f) * P.z + P.x;
    float cy = (L.y * 0.1f) * P.w + P.y;
    float w  = fexp_cr(L.z * 0.2f) * P.z;
    float h  = fexp_cr(L.w * 0.2f) * P.w;
    float4 o;
    o.x = cx - w * 0.5f;
    o.y = cy - h * 0.5f;
    o.z = cx + w * 0.5f;
    o.w = cy + h * 0.5f;
    ((float4*)boxes)[row] = o;
}

// ---------------------------------------------------------------------------
// Kernel C helpers: wave-synchronous (64-lane) suffix scan + bin selection.
// ---------------------------------------------------------------------------
__device__ __forceinline__ unsigned wave_suffix_incl(unsigned x, int lane) {
#pragma unroll
    for (int d = 1; d < 64; d <<= 1) {
        unsigned t = __shfl_down(x, d);
        if (lane + d < 64) x += t;
    }
    return x;
}

struct BinSel { int bin; int above; int cnt; int found; };

// Executed by wave 0 (tid<64). hist[4096] counts, partial[t]=sum of 16 bins.
// Finds largest bin index `bin` s.t. count(bins > bin) < Ktarget <= count(bins >= bin).
__device__ __forceinline__ BinSel wave_select_bin(const unsigned* hist,
                                                  const unsigned* partial,
                                                  int lane, unsigned Ktarget) {
    BinSel r;
    // group l = bins [64l, 64l+64)
    unsigned g = partial[4 * lane] + partial[4 * lane + 1]
               + partial[4 * lane + 2] + partial[4 * lane + 3];
    unsigned S = wave_suffix_incl(g, lane);        // S[l] = sum groups >= l
    unsigned total = __shfl(S, 0);
    if (total < Ktarget) { r.bin = -1; r.above = 0; r.cnt = 0; r.found = 0; return r; }
    unsigned Sn = __shfl_down(S, 1);
    if (lane == 63) Sn = 0u;
    bool ok = (S >= Ktarget) && (Sn < Ktarget);    // unique lane
    unsigned long long m = __ballot(ok);
    int lstar = __ffsll((unsigned long long)m) - 1;
    unsigned above_g = __shfl(Sn, lstar);          // count strictly above group
    // within group: bin = 64*lstar + lane
    unsigned h = hist[(lstar << 6) + lane];
    unsigned S2 = wave_suffix_incl(h, lane);       // bins >= lane within group
    unsigned S2n = __shfl_down(S2, 1);
    if (lane == 63) S2n = 0u;
    bool ok2 = (above_g + S2 >= Ktarget) && (above_g + S2n < Ktarget);
    unsigned long long m2 = __ballot(ok2);
    int l2 = __ffsll(m2) - 1;
    r.bin = (lstar << 6) + l2;
    r.above = (int)(above_g + __shfl(S2n, l2));    // strictly above bin
    r.cnt = (int)__shfl(h, l2);                    // count in bin
    r.found = 1;
    return r;
}

// ---------------------------------------------------------------------------
// Kernel C: per (b, c) — CONF-prefiltered radix-select top-100 (exact),
// register bitonic sort (256), wave-ballot greedy NMS (0 barriers in NMS).
// Only values > CONF can be kept or suppress (keep starts as `valid` in the
// reference), and they always occupy the first sorted slots — so the CONF
// prefilter is exact; slots beyond the filtered count output zeros.
// ---------------------------------------------------------------------------
__global__ __launch_bounds__(256) void topk_nms_kernel(
    const float* __restrict__ scores, const float* __restrict__ fg, int use_fg,
    const float* __restrict__ boxes,
    float* __restrict__ nms_scores, float* __restrict__ nms_boxes,
    float* __restrict__ keep_out)
{
#pragma clang fp contract(off)
    const int blk = blockIdx.x;        // b*80 + c
    const int b = blk / CM1;
    const int c = blk - b * CM1;
    const int tid = threadIdx.x;
    const int lane = tid & 63;
    const int wave = tid >> 6;

    __shared__ __align__(16) unsigned hist[4096];   // 16 KB, overlaid below
    __shared__ unsigned partial[256];
    __shared__ unsigned scnt;
    __shared__ unsigned s_T;
    __shared__ int s_b1, s_above, s_refine;

    // overlays on dead hist space (hist is dead once s_T is fixed):
    unsigned long long* cand = (unsigned long long*)hist;       // [0,2048) B
    float (*sbx)[4] = (float (*)[4])(hist + 512);               // [2048,3648) B
    float* sarea  = (float*)(hist + 912);                       // [3648,4048)
    float* sscore = (float*)(hist + 1012);                      // [4048,4448)
    int*   skeep  = (int*)(hist + 1112);                        // [4448,4848)

    const unsigned CONFB = __float_as_uint(CONF);

    const float* src = use_fg ? (fg + ((size_t)(b * CM1 + c)) * NN)
                              : (scores + ((size_t)b * NN) * CC + (c + 1));

    // ---- zero histogram ----
    uint4* h4z = (uint4*)hist;
    const uint4 z4 = make_uint4(0u, 0u, 0u, 0u);
    for (int i = tid; i < 1024; i += 256) h4z[i] = z4;
    __syncthreads();

    // ---- pass 1: histogram on top 12 bits, values > CONF only ----
    if (use_fg) {
        const float4* s4 = (const float4*)src;
        for (int i = tid; i < NN / 4; i += 256) {
            float4 v = s4[i];
            unsigned q0 = __float_as_uint(v.x), q1 = __float_as_uint(v.y);
            unsigned q2 = __float_as_uint(v.z), q3 = __float_as_uint(v.w);
            if (q0 > CONFB) atomicAdd(&hist[q0 >> 20], 1u);
            if (q1 > CONFB) atomicAdd(&hist[q1 >> 20], 1u);
            if (q2 > CONFB) atomicAdd(&hist[q2 >> 20], 1u);
            if (q3 > CONFB) atomicAdd(&hist[q3 >> 20], 1u);
        }
    } else {
        for (int n = tid; n < NN; n += 256) {
            unsigned bits = __float_as_uint(src[(size_t)n * CC]);
            if (bits > CONFB) atomicAdd(&hist[bits >> 20], 1u);
        }
    }
    __syncthreads();

    // ---- partial sums (16 bins / thread, vectorized LDS reads) ----
    {
        const uint4* h4 = (const uint4*)hist;
        unsigned s = 0;
#pragma unroll
        for (int q = 0; q < 4; ++q) {
            uint4 u = h4[tid * 4 + q];
            s += u.x + u.y + u.z + u.w;
        }
        partial[tid] = s;
    }
    __syncthreads();

    // ---- wave-parallel threshold selection ----
    if (tid < 64) {
        BinSel r = wave_select_bin(hist, partial, lane, (unsigned)KK);
        if (lane == 0) {
            scnt = 0u;
            if (!r.found) {                        // fewer than KK values > CONF
                s_T = 0u; s_refine = 0; s_b1 = -1; s_above = 0;
            } else {
                s_b1 = r.bin; s_above = r.above;
                s_refine = (r.above + r.cnt > CAP) ? 1 : 0;
                s_T = ((unsigned)r.bin) << 20;
            }
        }
    }
    __syncthreads();

    // ---- optional refine on bits [19:8] if boundary bin too dense ----
    if (s_refine) {
        const int b1 = s_b1;
        for (int i = tid; i < 1024; i += 256) h4z[i] = z4;
        __syncthreads();
        if (use_fg) {
            const float4* s4 = (const float4*)src;
            for (int i = tid; i < NN / 4; i += 256) {
                float4 v = s4[i];
                unsigned qq[4] = {__float_as_uint(v.x), __float_as_uint(v.y),
                                  __float_as_uint(v.z), __float_as_uint(v.w)};
#pragma unroll
                for (int q = 0; q < 4; ++q)
                    if (qq[q] > CONFB && (int)(qq[q] >> 20) == b1)
                        atomicAdd(&hist[(qq[q] >> 8) & 0xFFFu], 1u);
            }
        } else {
            for (int n = tid; n < NN; n += 256) {
                unsigned bits = __float_as_uint(src[(size_t)n * CC]);
                if (bits > CONFB && (int)(bits >> 20) == b1)
                    atomicAdd(&hist[(bits >> 8) & 0xFFFu], 1u);
            }
        }
        __syncthreads();
        {
            const uint4* h4 = (const uint4*)hist;
            unsigned s = 0;
#pragma unroll
            for (int q = 0; q < 4; ++q) {
                uint4 u = h4[tid * 4 + q];
                s += u.x + u.y + u.z + u.w;
            }
            partial[tid] = s;
        }
        __syncthreads();
        if (tid < 64) {
            BinSel r2 = wave_select_bin(hist, partial, lane, (unsigned)(KK - s_above));
            if (lane == 0 && r2.found)
                s_T = (((unsigned)s_b1) << 20) | (((unsigned)r2.bin) << 8);
        }
        __syncthreads();
    }

    // ---- collect candidates: bits > CONFB && bits >= T ----
    const unsigned T = s_T;
    if (use_fg) {
        const float4* s4 = (const float4*)src;
        for (int i = tid; i < NN / 4; i += 256) {
            float4 v = s4[i];
            unsigned qq[4] = {__float_as_uint(v.x), __float_as_uint(v.y),
                              __float_as_uint(v.z), __float_as_uint(v.w)};
#pragma unroll
            for (int q = 0; q < 4; ++q) {
                unsigned bits = qq[q];
                if (bits > CONFB && bits >= T) {
                    unsigned pos = atomicAdd(&scnt, 1u);
                    if (pos < CAP)
                        cand[pos] = (((unsigned long long)bits) << 32)
                                  | (unsigned)(0xFFFFFFFFu - (unsigned)(i * 4 + q));
                }
            }
        }
    } else {
        for (int n = tid; n < NN; n += 256) {
            unsigned bits = __float_as_uint(src[(size_t)n * CC]);
            if (bits > CONFB && bits >= T) {
                unsigned pos = atomicAdd(&scnt, 1u);
                if (pos < CAP)
                    cand[pos] = (((unsigned long long)bits) << 32)
                              | (unsigned)(0xFFFFFFFFu - (unsigned)n);
            }
        }
    }
    __syncthreads();
    unsigned cnt = scnt; if (cnt > CAP) cnt = CAP;
    if ((unsigned)tid >= cnt) cand[tid] = 0ull;     // pads sort to the end
    __syncthreads();

    // ---- register bitonic sort, descending, 256 elems (1/thread) ----
    // 33 __shfl_xor stages + 3 cross-wave LDS stages (6 barriers total)
    unsigned long long v = cand[tid];
    for (unsigned k = 2; k <= 256; k <<= 1) {
        for (unsigned j = k >> 1; j > 0; j >>= 1) {
            unsigned long long p;
            if (j >= 64) {
                __syncthreads();
                cand[tid] = v;
                __syncthreads();
                p = cand[tid ^ j];
            } else {
                p = __shfl_xor(v, (int)j, 64);
            }
            bool keep_max = (((tid & j) == 0u) == ((tid & k) == 0u));
            bool take = ((p > v) == keep_max);
            v = take ? p : v;
        }
    }
    __syncthreads();

    // ---- extract top-100 (thread tid holds rank tid), gather boxes ----
    if (tid < KK) {
        unsigned bits = (unsigned)(v >> 32);
        if (bits != 0u) {
            unsigned n = 0xFFFFFFFFu - (unsigned)(v & 0xFFFFFFFFu);
            float s = __uint_as_float(bits);
            sscore[tid] = s;
            skeep[tid] = (s > CONF) ? 1 : 0;
            float4 bx = ((const float4*)boxes)[(size_t)b * NN + n];
            sbx[tid][0] = bx.x; sbx[tid][1] = bx.y; sbx[tid][2] = bx.z; sbx[tid][3] = bx.w;
            sarea[tid] = fmaxf(bx.z - bx.x, 0.f) * fmaxf(bx.w - bx.y, 0.f);
        } else {                                    // pad slot
            sscore[tid] = 0.f; skeep[tid] = 0;
            sbx[tid][0] = 0.f; sbx[tid][1] = 0.f; sbx[tid][2] = 0.f; sbx[tid][3] = 0.f;
            sarea[tid] = 0.f;
        }
    }
    __syncthreads();

    // ---- greedy NMS, wave 0 only, ballot-mask state, ZERO barriers ----
    if (wave == 0) {
        const int j1 = lane + 64;
        const bool hasj1 = (j1 < KK);
        float4 B0 = make_float4(sbx[lane][0], sbx[lane][1], sbx[lane][2], sbx[lane][3]);
        float a0 = sarea[lane];
        float4 B1 = hasj1 ? make_float4(sbx[j1][0], sbx[j1][1], sbx[j1][2], sbx[j1][3])
                          : make_float4(0.f, 0.f, 0.f, 0.f);
        float a1 = hasj1 ? sarea[j1] : 0.f;
        unsigned long long k0 = __ballot(skeep[lane] != 0);           // bits j=0..63
        unsigned long long k1 = __ballot(hasj1 && skeep[j1] != 0);    // bits j=64..99
        for (int i = 0; i < KK - 1; ++i) {
            bool alive = (i < 64) ? ((k0 >> i) & 1ull) : ((k1 >> (i - 64)) & 1ull);
            if (!alive) continue;            // wave-uniform skip
            float bix = sbx[i][0], biy = sbx[i][1], biz = sbx[i][2], biw = sbx[i][3];
            float ai = sarea[i];
            // j0 = lane
            float xx1 = fmaxf(bix, B0.x), yy1 = fmaxf(biy, B0.y);
            float xx2 = fminf(biz, B0.z), yy2 = fminf(biw, B0.w);
            float w0 = fmaxf(xx2 - xx1, 0.f), h0 = fmaxf(yy2 - yy1, 0.f);
            float inter0 = w0 * h0;
            float den0 = ((ai + a0) - inter0) + 1e-8f;
            bool s0 = (lane > i) && (inter0 / den0 > NMSTHR);
            // j1 = lane + 64
            float xb1 = fmaxf(bix, B1.x), yb1 = fmaxf(biy, B1.y);
            float xb2 = fminf(biz, B1.z), yb2 = fminf(biw, B1.w);
            float wb = fmaxf(xb2 - xb1, 0.f), hb = fmaxf(yb2 - yb1, 0.f);
            float interb = wb * hb;
            float denb = ((ai + a1) - interb) + 1e-8f;
            bool s1 = hasj1 && (j1 > i) && (interb / denb > NMSTHR);
            unsigned long long sup0 = __ballot(s0);
            unsigned long long sup1 = __ballot(s1);
            k0 &= ~sup0;
            k1 &= ~sup1;
        }
        skeep[lane] = (int)((k0 >> lane) & 1ull);
        if (hasj1) skeep[j1] = (int)((k1 >> lane) & 1ull);
    }
    __syncthreads();

    // ---- outputs ----
    if (tid < KK) {
        int kf = skeep[tid];
        size_t oidx = (size_t)blk * KK + tid;
        nms_scores[oidx] = kf ? sscore[tid] : 0.f;
        keep_out[oidx]   = kf ? 1.f : 0.f;
        float4 ob;
        ob.x = kf ? sbx[tid][0] : 0.f;
        ob.y = kf ? sbx[tid][1] : 0.f;
        ob.z = kf ? sbx[tid][2] : 0.f;
        ob.w = kf ? sbx[tid][3] : 0.f;
        ((float4*)nms_boxes)[oidx] = ob;
    }
}

extern "C" void kernel_launch(void* const* d_in, const int* in_sizes, int n_in,
                              void* d_out, int out_size, void* d_ws, size_t ws_size,
                              hipStream_t stream) {
    const float* logits = (const float*)d_in[0];
    const float* bbox   = (const float*)d_in[1];
    const float* priors = (const float*)d_in[2];

    float* out = (float*)d_out;
    float* scores     = out;
    float* boxes      = scores + (size_t)BB * NN * CC;
    float* nms_scores = boxes + (size_t)BB * NN * 4;
    float* nms_boxes  = nms_scores + (size_t)BB * CM1 * KK;
    float* keep_out   = nms_boxes + (size_t)BB * CM1 * KK * 4;

    size_t fg_bytes = (size_t)BB * CM1 * NN * sizeof(float);
    int use_fg = (ws_size >= fg_bytes) ? 1 : 0;
    float* fg = (float*)d_ws;

    int rows = BB * NN;
    int blocksA = (rows + 255) / 256;
    softmax_kernel<<<BB * TPB, 256, 0, stream>>>(logits, scores, fg, use_fg);
    decode_kernel<<<blocksA, 256, 0, stream>>>(bbox, priors, boxes);
    topk_nms_kernel<<<BB * CM1, 256, 0, stream>>>(scores, fg, use_fg, boxes,
                                                  nms_scores, nms_boxes, keep_out);
}